// Round 9
// baseline (611.405 us; speedup 1.0000x reference)
//
#include <hip/hip_runtime.h>
#include <hip/hip_bf16.h>
#include <math.h>

#define L 1024
typedef __hip_bfloat16 bf;
typedef __attribute__((ext_vector_type(8))) short short8;

__device__ __forceinline__ float b2f(bf v) { return __bfloat162float(v); }
__device__ __forceinline__ bf f2b(float v) { return __float2bfloat16(v); }
__device__ __forceinline__ float bits2f(short s) {
  union { unsigned u; float f; } cv; cv.u = ((unsigned)(unsigned short)s) << 16; return cv.f;
}

// ---- k_front: 1x1 conv + BN + exact GELU + in_proj -> xm(bf16), z(bf16) ----
__global__ __launch_bounds__(256) void k_front(
    const float* __restrict__ x, const float* __restrict__ conv_w,
    const float* __restrict__ conv_b, const float* __restrict__ gamma,
    const float* __restrict__ beta, const float* __restrict__ mean,
    const float* __restrict__ var, const float* __restrict__ ipw,
    bf* __restrict__ xm, bf* __restrict__ z) {
  int tid = blockIdx.x * 256 + threadIdx.x;   // 65536 = (b,l)
  int l = tid & (L - 1);
  int b = tid >> 10;
  const float* xp = x + (size_t)b * 65536 + l;
  float xv[64];
#pragma unroll
  for (int c = 0; c < 64; ++c) xv[c] = xp[c * L];
  float h[32];
#pragma unroll
  for (int d = 0; d < 32; ++d) {
    float acc = conv_b[d];
#pragma unroll
    for (int c = 0; c < 64; ++c) acc = fmaf(xv[c], conv_w[d * 64 + c], acc);
    float sc = gamma[d] * rsqrtf(var[d] + 1e-5f);
    acc = (acc - mean[d]) * sc + beta[d];
    h[d] = 0.5f * acc * (1.0f + erff(acc * 0.70710678118654752f));
  }
  for (int j = 0; j < 64; ++j) {
    float a0 = 0.f, a1 = 0.f;
#pragma unroll
    for (int d = 0; d < 32; ++d) {
      a0 = fmaf(h[d], ipw[j * 32 + d], a0);
      a1 = fmaf(h[d], ipw[(j + 64) * 32 + d], a1);
    }
    xm[(size_t)b * 65536 + j * L + l] = f2b(a0);
    z [(size_t)b * 65536 + j * L + l] = f2b(a1);
  }
}

// ---- k_mid: depthwise conv1d + SiLU + x_proj + dt(softplus) ----
// B/C written pre-permuted for the scan's LDS staging:
// slot s = (l&63)*16 + (l>>6)  (chunk c=l>>6, step i=l&63 -> s=i*16+c)
__global__ __launch_bounds__(256) void k_mid(
    const bf* __restrict__ xm, const float* __restrict__ c1w,
    const float* __restrict__ c1b, const float* __restrict__ xpw,
    const float* __restrict__ dtw, const float* __restrict__ dtbp,
    bf* __restrict__ u, bf* __restrict__ dt_o,
    bf* __restrict__ Bt, bf* __restrict__ Ct) {
  int tid = blockIdx.x * 256 + threadIdx.x;   // (b,l)
  int l = tid & (L - 1);
  int b = tid >> 10;
  float um[64];
#pragma unroll
  for (int d = 0; d < 64; ++d) {
    float acc = c1b[d];
#pragma unroll
    for (int k = 0; k < 4; ++k) {
      int ls = l - 3 + k;
      float v = (ls >= 0) ? b2f(xm[(size_t)b * 65536 + d * L + ls]) : 0.f;
      acc = fmaf(c1w[d * 4 + k], v, acc);
    }
    float s = acc / (1.f + __expf(-acc));
    um[d] = s;
    u[(size_t)b * 65536 + d * L + l] = f2b(s);
  }
  float xd[34];
  for (int k = 0; k < 34; ++k) {
    float acc = 0.f;
#pragma unroll
    for (int d = 0; d < 64; ++d) acc = fmaf(um[d], xpw[k * 64 + d], acc);
    xd[k] = acc;
  }
#pragma unroll
  for (int d = 0; d < 64; ++d) {
    float raw = fmaf(xd[0], dtw[d * 2], fmaf(xd[1], dtw[d * 2 + 1], dtbp[d]));
    float sp = fmaxf(raw, 0.f) + log1pf(__expf(-fabsf(raw)));
    dt_o[(size_t)b * 65536 + d * L + l] = f2b(sp);
  }
  int s = ((l & 63) << 4) | (l >> 6);   // LDS-ready slot
#pragma unroll
  for (int n2 = 0; n2 < 16; ++n2) {
    Bt[(size_t)b * 16384 + s * 16 + n2] = f2b(xd[2 + n2]);
    Ct[(size_t)b * 16384 + s * 16 + n2] = f2b(xd[18 + n2]);
  }
}

// ---- k_scan: block = (b, 16 d's); B/C panels staged in LDS (64 KB) ----
__global__ __launch_bounds__(256, 2) void k_scan(
    const bf* __restrict__ u, const bf* __restrict__ dt,
    const bf* __restrict__ z, const bf* __restrict__ Bt,
    const bf* __restrict__ Ct, const float* __restrict__ A_log,
    const float* __restrict__ Dp, float* __restrict__ pooled64) {
  __shared__ bf Bsh[16384];   // 32 KB, slot s=i*16+c, 16 n per slot
  __shared__ bf Csh[16384];   // 32 KB
  int phys = blockIdx.x;      // 256 blocks
  int b = phys & 63;          // same-b blocks: phys%8 identical -> same XCD
  int dgrp = phys >> 6;       // 0..3
  int t = threadIdx.x;
  int d_local = t >> 4, c = t & 15;
  int d = dgrp * 16 + d_local;
  int g = b * 64 + d;

  // stage both panels: 2048 short8 each, 8 per thread
  {
    const short8* Bg8 = (const short8*)(Bt + (size_t)b * 16384);
    const short8* Cg8 = (const short8*)(Ct + (size_t)b * 16384);
    short8* Bs8 = (short8*)Bsh;
    short8* Cs8 = (short8*)Csh;
#pragma unroll
    for (int q = 0; q < 8; ++q) {
      Bs8[t + q * 256] = Bg8[t + q * 256];
      Cs8[t + q * 256] = Cg8[t + q * 256];
    }
  }
  __syncthreads();

  float An[16];
#pragma unroll
  for (int n = 0; n < 16; ++n) An[n] = -__expf(A_log[d * 16 + n]);
  const short8* dps = (const short8*)(dt + (size_t)g * L + c * 64);
  const short8* ups = (const short8*)(u  + (size_t)g * L + c * 64);
  const short8* zps = (const short8*)(z  + (size_t)g * L + c * 64);

  float h[16];
#pragma unroll
  for (int n = 0; n < 16; ++n) h[n] = 0.f;
  float sumdt = 0.f;
  // ---- sweep A: local scan over 64 steps from h=0 ----
#pragma unroll
  for (int tile = 0; tile < 4; ++tile) {
    short8 d8a = dps[tile * 2], d8b = dps[tile * 2 + 1];
    short8 u8a = ups[tile * 2], u8b = ups[tile * 2 + 1];
#pragma unroll
    for (int i2 = 0; i2 < 16; ++i2) {
      float dtv = bits2f((i2 < 8) ? d8a[i2 & 7] : d8b[i2 & 7]);
      float uv  = bits2f((i2 < 8) ? u8a[i2 & 7] : u8b[i2 & 7]);
      int s = (tile * 16 + i2) * 16 + c;
      const short8* row = (const short8*)(Bsh + s * 16);
      short8 b0 = row[0], b1 = row[1];
      float du = dtv * uv;
      sumdt += dtv;
#pragma unroll
      for (int n = 0; n < 16; ++n) {
        float a = __expf(dtv * An[n]);
        float Bv = bits2f((n < 8) ? b0[n & 7] : b1[n & 7]);
        h[n] = fmaf(a, h[n], du * Bv);
      }
    }
  }
  float P[16];
#pragma unroll
  for (int n = 0; n < 16; ++n) P[n] = __expf(An[n] * sumdt);

  // ---- compose over 16 chunks (width-16 Hillis-Steele) ----
#pragma unroll
  for (int s = 1; s < 16; s <<= 1) {
    bool act = (c >= s);
#pragma unroll
    for (int n = 0; n < 16; ++n) {
      float Po = __shfl_up(P[n], (unsigned)s, 16);
      float Oo = __shfl_up(h[n], (unsigned)s, 16);
      if (act) { h[n] = fmaf(P[n], Oo, h[n]); P[n] *= Po; }
    }
  }
#pragma unroll
  for (int n = 0; n < 16; ++n) {
    float v = __shfl_up(h[n], 1u, 16);
    h[n] = (c == 0) ? 0.f : v;     // exclusive prefix = h_in
  }

  // ---- sweep B: true scan from h_in, gate + pool ----
  float Dd = Dp[d];
  float pooled = 0.f;
#pragma unroll
  for (int tile = 0; tile < 4; ++tile) {
    short8 d8a = dps[tile * 2], d8b = dps[tile * 2 + 1];
    short8 u8a = ups[tile * 2], u8b = ups[tile * 2 + 1];
    short8 z8a = zps[tile * 2], z8b = zps[tile * 2 + 1];
#pragma unroll
    for (int i2 = 0; i2 < 16; ++i2) {
      float dtv = bits2f((i2 < 8) ? d8a[i2 & 7] : d8b[i2 & 7]);
      float uv  = bits2f((i2 < 8) ? u8a[i2 & 7] : u8b[i2 & 7]);
      float zv  = bits2f((i2 < 8) ? z8a[i2 & 7] : z8b[i2 & 7]);
      int s = (tile * 16 + i2) * 16 + c;
      const short8* rowB = (const short8*)(Bsh + s * 16);
      const short8* rowC = (const short8*)(Csh + s * 16);
      short8 b0 = rowB[0], b1 = rowB[1];
      short8 c0 = rowC[0], c1 = rowC[1];
      float du = dtv * uv;
      float y0 = 0.f, y1 = 0.f, y2 = 0.f, y3 = 0.f;
#pragma unroll
      for (int n = 0; n < 16; ++n) {
        float a = __expf(dtv * An[n]);
        float Bv = bits2f((n < 8) ? b0[n & 7] : b1[n & 7]);
        h[n] = fmaf(a, h[n], du * Bv);
        float Cv = bits2f((n < 8) ? c0[n & 7] : c1[n & 7]);
        if ((n & 3) == 0)      y0 = fmaf(h[n], Cv, y0);
        else if ((n & 3) == 1) y1 = fmaf(h[n], Cv, y1);
        else if ((n & 3) == 2) y2 = fmaf(h[n], Cv, y2);
        else                   y3 = fmaf(h[n], Cv, y3);
      }
      float y = (y0 + y1) + (y2 + y3);
      float yd = fmaf(uv, Dd, y) * (zv / (1.f + __expf(-zv)));
      pooled += yd;
    }
  }
#pragma unroll
  for (int s = 1; s < 16; s <<= 1) pooled += __shfl_xor(pooled, s, 16);
  if (c == 0) pooled64[g] = pooled;
}

// ---- k_fc: out_proj(mean) + fc (out_proj commutes with mean-pool) ----
__global__ __launch_bounds__(128) void k_fc(
    const float* __restrict__ pooled64, const float* __restrict__ opw,
    const float* __restrict__ fcw, const float* __restrict__ fcb,
    float* __restrict__ out) {
  __shared__ float p64[64];
  __shared__ float o32[32];
  int b = blockIdx.x, t = threadIdx.x;
  if (t < 64) p64[t] = pooled64[b * 64 + t];
  __syncthreads();
  if (t < 32) {
    float s = 0.f;
#pragma unroll
    for (int d0 = 0; d0 < 64; ++d0) s = fmaf(p64[d0], opw[t * 64 + d0], s);
    o32[t] = s * (1.f / 1024.f);
  }
  __syncthreads();
  float acc = fcb[t];
#pragma unroll
  for (int j = 0; j < 32; ++j) acc = fmaf(o32[j], fcw[t * 32 + j], acc);
  out[b * 128 + t] = acc;
}

extern "C" void kernel_launch(void* const* d_in, const int* in_sizes, int n_in,
                              void* d_out, int out_size, void* d_ws, size_t ws_size,
                              hipStream_t stream) {
  const float* x      = (const float*)d_in[0];
  const float* conv_w = (const float*)d_in[1];
  const float* conv_b = (const float*)d_in[2];
  const float* bn_g   = (const float*)d_in[3];
  const float* bn_b   = (const float*)d_in[4];
  const float* bn_m   = (const float*)d_in[5];
  const float* bn_v   = (const float*)d_in[6];
  const float* ipw    = (const float*)d_in[7];
  const float* c1w    = (const float*)d_in[8];
  const float* c1b    = (const float*)d_in[9];
  const float* xpw    = (const float*)d_in[10];
  const float* dtw    = (const float*)d_in[11];
  const float* dtbp   = (const float*)d_in[12];
  const float* A_log  = (const float*)d_in[13];
  const float* Dp     = (const float*)d_in[14];
  const float* opw    = (const float*)d_in[15];
  const float* fcw    = (const float*)d_in[16];
  const float* fcb    = (const float*)d_in[17];

  char* ws = (char*)d_ws;
  bf* xmb = (bf*)(ws + 0);               // 8 MB
  bf* zb  = (bf*)(ws + 8388608);         // 8 MB
  bf* ub  = (bf*)(ws + 16777216);        // 8 MB
  bf* dtb = (bf*)(ws + 25165824);        // 8 MB
  bf* Btb = (bf*)(ws + 33554432);        // 2 MB (LDS-slot permuted)
  bf* Ctb = (bf*)(ws + 35651584);        // 2 MB (LDS-slot permuted)
  float* pooled = (float*)(ws + 37748736); // 16 KB

  hipLaunchKernelGGL(k_front, dim3(256), dim3(256), 0, stream,
                     x, conv_w, conv_b, bn_g, bn_b, bn_m, bn_v, ipw, xmb, zb);
  hipLaunchKernelGGL(k_mid, dim3(256), dim3(256), 0, stream,
                     xmb, c1w, c1b, xpw, dtw, dtbp, ub, dtb, Btb, Ctb);
  hipLaunchKernelGGL(k_scan, dim3(256), dim3(256), 0, stream,
                     ub, dtb, zb, Btb, Ctb, A_log, Dp, pooled);
  hipLaunchKernelGGL(k_fc, dim3(64), dim3(128), 0, stream,
                     pooled, opw, fcw, fcb, (float*)d_out);
}

// Round 10
// 261.744 us; speedup vs baseline: 2.3359x; 2.3359x over previous
//
#include <hip/hip_runtime.h>
#include <hip/hip_bf16.h>
#include <math.h>

#define L 1024
typedef __hip_bfloat16 bf;
typedef __attribute__((ext_vector_type(8))) short short8;

__device__ __forceinline__ float b2f(bf v) { return __bfloat162float(v); }
__device__ __forceinline__ bf f2b(float v) { return __float2bfloat16(v); }
__device__ __forceinline__ float bits2f(short s) {
  union { unsigned u; float f; } cv; cv.u = ((unsigned)(unsigned short)s) << 16; return cv.f;
}

// ---- k_front: 1x1 conv + BN + exact GELU + in_proj -> xm(bf16), z(bf16) ----
__global__ __launch_bounds__(256) void k_front(
    const float* __restrict__ x, const float* __restrict__ conv_w,
    const float* __restrict__ conv_b, const float* __restrict__ gamma,
    const float* __restrict__ beta, const float* __restrict__ mean,
    const float* __restrict__ var, const float* __restrict__ ipw,
    bf* __restrict__ xm, bf* __restrict__ z) {
  int tid = blockIdx.x * 256 + threadIdx.x;   // 65536 = (b,l)
  int l = tid & (L - 1);
  int b = tid >> 10;
  const float* xp = x + (size_t)b * 65536 + l;
  float xv[64];
#pragma unroll
  for (int c = 0; c < 64; ++c) xv[c] = xp[c * L];
  float h[32];
#pragma unroll
  for (int d = 0; d < 32; ++d) {
    float acc = conv_b[d];
#pragma unroll
    for (int c = 0; c < 64; ++c) acc = fmaf(xv[c], conv_w[d * 64 + c], acc);
    float sc = gamma[d] * rsqrtf(var[d] + 1e-5f);
    acc = (acc - mean[d]) * sc + beta[d];
    h[d] = 0.5f * acc * (1.0f + erff(acc * 0.70710678118654752f));
  }
  for (int j = 0; j < 64; ++j) {
    float a0 = 0.f, a1 = 0.f;
#pragma unroll
    for (int d = 0; d < 32; ++d) {
      a0 = fmaf(h[d], ipw[j * 32 + d], a0);
      a1 = fmaf(h[d], ipw[(j + 64) * 32 + d], a1);
    }
    xm[(size_t)b * 65536 + j * L + l] = f2b(a0);
    z [(size_t)b * 65536 + j * L + l] = f2b(a1);
  }
}

// ---- k_mid: depthwise conv1d + SiLU + x_proj + dt(softplus) ----
// B/C written pre-permuted for the scan: slot s = (l&31)*32 + (l>>5)
// (step i = l&31, chunk c = l>>5 -> s = i*32 + c)
__global__ __launch_bounds__(256) void k_mid(
    const bf* __restrict__ xm, const float* __restrict__ c1w,
    const float* __restrict__ c1b, const float* __restrict__ xpw,
    const float* __restrict__ dtw, const float* __restrict__ dtbp,
    bf* __restrict__ u, bf* __restrict__ dt_o,
    bf* __restrict__ Bt, bf* __restrict__ Ct) {
  int tid = blockIdx.x * 256 + threadIdx.x;   // (b,l)
  int l = tid & (L - 1);
  int b = tid >> 10;
  float um[64];
#pragma unroll
  for (int d = 0; d < 64; ++d) {
    float acc = c1b[d];
#pragma unroll
    for (int k = 0; k < 4; ++k) {
      int ls = l - 3 + k;
      float v = (ls >= 0) ? b2f(xm[(size_t)b * 65536 + d * L + ls]) : 0.f;
      acc = fmaf(c1w[d * 4 + k], v, acc);
    }
    float s = acc / (1.f + __expf(-acc));
    um[d] = s;
    u[(size_t)b * 65536 + d * L + l] = f2b(s);
  }
  float xd[34];
  for (int k = 0; k < 34; ++k) {
    float acc = 0.f;
#pragma unroll
    for (int d = 0; d < 64; ++d) acc = fmaf(um[d], xpw[k * 64 + d], acc);
    xd[k] = acc;
  }
#pragma unroll
  for (int d = 0; d < 64; ++d) {
    float raw = fmaf(xd[0], dtw[d * 2], fmaf(xd[1], dtw[d * 2 + 1], dtbp[d]));
    float sp = fmaxf(raw, 0.f) + log1pf(__expf(-fabsf(raw)));
    dt_o[(size_t)b * 65536 + d * L + l] = f2b(sp);
  }
  int s = ((l & 31) << 5) | (l >> 5);   // LDS-ready slot
#pragma unroll
  for (int n2 = 0; n2 < 16; ++n2) {
    Bt[(size_t)b * 16384 + s * 16 + n2] = f2b(xd[2 + n2]);
    Ct[(size_t)b * 16384 + s * 16 + n2] = f2b(xd[18 + n2]);
  }
}

// ---- k_scan: single-sweep chunked scan, B/C in LDS, fused gate+pool ----
// block = (b, 8 d's), 256 thr = 8 d x 32 chunks of 32 steps. Grid 512.
// Sweep from h=0 accumulating: base = sum s_l*(y_local + u*D),
// q[n] = sum s_l*C_l[n]*pi_l[n]; pi = running decay (= compose P at end).
// Compose (width-32 shfl) -> h_in; pooled = base + q.h_in.
__global__ __launch_bounds__(256, 2) void k_scan(
    const bf* __restrict__ u, const bf* __restrict__ dt,
    const bf* __restrict__ z, const bf* __restrict__ Bt,
    const bf* __restrict__ Ct, const float* __restrict__ A_log,
    const float* __restrict__ Dp, float* __restrict__ pooled64) {
  __shared__ bf Bsh[16384];   // 32 KB, slot s=i*32+c, 16 n per slot
  __shared__ bf Csh[16384];   // 32 KB
  int phys = blockIdx.x;      // 512 blocks
  int b = phys & 63;          // same-b blocks share phys%8 -> same XCD
  int dgrp = phys >> 6;       // 0..7
  int t = threadIdx.x;
  int d_local = t >> 5, c = t & 31;
  int d = dgrp * 8 + d_local;
  int g = b * 64 + d;

  // stage both panels: 2048 short8 each, 8 per thread
  {
    const short8* Bg8 = (const short8*)(Bt + (size_t)b * 16384);
    const short8* Cg8 = (const short8*)(Ct + (size_t)b * 16384);
    short8* Bs8 = (short8*)Bsh;
    short8* Cs8 = (short8*)Csh;
#pragma unroll
    for (int q = 0; q < 8; ++q) {
      Bs8[t + q * 256] = Bg8[t + q * 256];
      Cs8[t + q * 256] = Cg8[t + q * 256];
    }
  }
  __syncthreads();

  float An[16];
#pragma unroll
  for (int n = 0; n < 16; ++n) An[n] = -__expf(A_log[d * 16 + n]);
  const short8* dps = (const short8*)(dt + (size_t)g * L + c * 32);
  const short8* ups = (const short8*)(u  + (size_t)g * L + c * 32);
  const short8* zps = (const short8*)(z  + (size_t)g * L + c * 32);
  float Dd = Dp[d];

  float h[16], pi[16], q[16];
#pragma unroll
  for (int n = 0; n < 16; ++n) { h[n] = 0.f; pi[n] = 1.f; q[n] = 0.f; }
  float base = 0.f;

#pragma unroll 1
  for (int t8 = 0; t8 < 4; ++t8) {
    short8 d8 = dps[t8], u8 = ups[t8], z8 = zps[t8];
#pragma unroll
    for (int i = 0; i < 8; ++i) {
      int step = t8 * 8 + i;
      float dtv = bits2f(d8[i]);
      float uv  = bits2f(u8[i]);
      float zv  = bits2f(z8[i]);
      float sv  = zv / (1.f + __expf(-zv));   // silu(z)
      float du  = dtv * uv;
      int slot = step * 32 + c;
      const short8* rowB = (const short8*)(Bsh + slot * 16);
      const short8* rowC = (const short8*)(Csh + slot * 16);
      short8 b0 = rowB[0], b1 = rowB[1];
      short8 c0 = rowC[0], c1 = rowC[1];
      float y0 = 0.f, y1 = 0.f;
#pragma unroll
      for (int n = 0; n < 16; ++n) {
        float a = __expf(dtv * An[n]);
        float Bv = bits2f((n < 8) ? b0[n & 7] : b1[n & 7]);
        float Cv = bits2f((n < 8) ? c0[n & 7] : c1[n & 7]);
        h[n] = fmaf(a, h[n], du * Bv);
        pi[n] *= a;
        if (n & 1) y1 = fmaf(h[n], Cv, y1); else y0 = fmaf(h[n], Cv, y0);
        q[n] = fmaf(sv * pi[n], Cv, q[n]);
      }
      base = fmaf(sv, (y0 + y1) + uv * Dd, base);
    }
  }

  // ---- compose over 32 chunks (width-32 Hillis-Steele): P=pi, O=h ----
#pragma unroll
  for (int s = 1; s < 32; s <<= 1) {
    bool act = (c >= s);
#pragma unroll
    for (int n = 0; n < 16; ++n) {
      float Po = __shfl_up(pi[n], (unsigned)s, 32);
      float Oo = __shfl_up(h[n], (unsigned)s, 32);
      if (act) { h[n] = fmaf(pi[n], Oo, h[n]); pi[n] *= Po; }
    }
  }
  float pooled = base;
#pragma unroll
  for (int n = 0; n < 16; ++n) {
    float v = __shfl_up(h[n], 1u, 32);
    float hin = (c == 0) ? 0.f : v;       // exclusive prefix = h_in
    pooled = fmaf(q[n], hin, pooled);
  }
#pragma unroll
  for (int s = 1; s < 32; s <<= 1) pooled += __shfl_xor(pooled, s, 32);
  if (c == 0) pooled64[g] = pooled;
}

// ---- k_fc: out_proj(mean) + fc (out_proj commutes with mean-pool) ----
__global__ __launch_bounds__(128) void k_fc(
    const float* __restrict__ pooled64, const float* __restrict__ opw,
    const float* __restrict__ fcw, const float* __restrict__ fcb,
    float* __restrict__ out) {
  __shared__ float p64[64];
  __shared__ float o32[32];
  int b = blockIdx.x, t = threadIdx.x;
  if (t < 64) p64[t] = pooled64[b * 64 + t];
  __syncthreads();
  if (t < 32) {
    float s = 0.f;
#pragma unroll
    for (int d0 = 0; d0 < 64; ++d0) s = fmaf(p64[d0], opw[t * 64 + d0], s);
    o32[t] = s * (1.f / 1024.f);
  }
  __syncthreads();
  float acc = fcb[t];
#pragma unroll
  for (int j = 0; j < 32; ++j) acc = fmaf(o32[j], fcw[t * 32 + j], acc);
  out[b * 128 + t] = acc;
}

extern "C" void kernel_launch(void* const* d_in, const int* in_sizes, int n_in,
                              void* d_out, int out_size, void* d_ws, size_t ws_size,
                              hipStream_t stream) {
  const float* x      = (const float*)d_in[0];
  const float* conv_w = (const float*)d_in[1];
  const float* conv_b = (const float*)d_in[2];
  const float* bn_g   = (const float*)d_in[3];
  const float* bn_b   = (const float*)d_in[4];
  const float* bn_m   = (const float*)d_in[5];
  const float* bn_v   = (const float*)d_in[6];
  const float* ipw    = (const float*)d_in[7];
  const float* c1w    = (const float*)d_in[8];
  const float* c1b    = (const float*)d_in[9];
  const float* xpw    = (const float*)d_in[10];
  const float* dtw    = (const float*)d_in[11];
  const float* dtbp   = (const float*)d_in[12];
  const float* A_log  = (const float*)d_in[13];
  const float* Dp     = (const float*)d_in[14];
  const float* opw    = (const float*)d_in[15];
  const float* fcw    = (const float*)d_in[16];
  const float* fcb    = (const float*)d_in[17];

  char* ws = (char*)d_ws;
  bf* xmb = (bf*)(ws + 0);               // 8 MB
  bf* zb  = (bf*)(ws + 8388608);         // 8 MB
  bf* ub  = (bf*)(ws + 16777216);        // 8 MB
  bf* dtb = (bf*)(ws + 25165824);        // 8 MB
  bf* Btb = (bf*)(ws + 33554432);        // 2 MB (slot-permuted)
  bf* Ctb = (bf*)(ws + 35651584);        // 2 MB (slot-permuted)
  float* pooled = (float*)(ws + 37748736); // 16 KB

  hipLaunchKernelGGL(k_front, dim3(256), dim3(256), 0, stream,
                     x, conv_w, conv_b, bn_g, bn_b, bn_m, bn_v, ipw, xmb, zb);
  hipLaunchKernelGGL(k_mid, dim3(256), dim3(256), 0, stream,
                     xmb, c1w, c1b, xpw, dtw, dtbp, ub, dtb, Btb, Ctb);
  hipLaunchKernelGGL(k_scan, dim3(512), dim3(256), 0, stream,
                     ub, dtb, zb, Btb, Ctb, A_log, Dp, pooled);
  hipLaunchKernelGGL(k_fc, dim3(64), dim3(128), 0, stream,
                     pooled, opw, fcw, fcb, (float*)d_out);
}

// Round 11
// 187.973 us; speedup vs baseline: 3.2526x; 1.3925x over previous
//
#include <hip/hip_runtime.h>
#include <hip/hip_bf16.h>
#include <math.h>

#define L 1024
typedef __hip_bfloat16 bf;
typedef __attribute__((ext_vector_type(8))) short short8v;
typedef __attribute__((ext_vector_type(4))) short short4v;

__device__ __forceinline__ float b2f(bf v) { return __bfloat162float(v); }
__device__ __forceinline__ bf f2b(float v) { return __float2bfloat16(v); }
__device__ __forceinline__ float bits2f(short s) {
  union { unsigned u; float f; } cv; cv.u = ((unsigned)(unsigned short)s) << 16; return cv.f;
}
union Pack4 { short4v v; unsigned short e[4]; };
__device__ __forceinline__ unsigned short f2bits(float v) {
  union { bf b; unsigned short u; } cv; cv.b = __float2bfloat16(v); return cv.u;
}

// ---- k_front: 1x1 conv + BN + exact GELU + in_proj -> xm(bf16), z(bf16) ----
__global__ __launch_bounds__(256) void k_front(
    const float* __restrict__ x, const float* __restrict__ conv_w,
    const float* __restrict__ conv_b, const float* __restrict__ gamma,
    const float* __restrict__ beta, const float* __restrict__ mean,
    const float* __restrict__ var, const float* __restrict__ ipw,
    bf* __restrict__ xm, bf* __restrict__ z) {
  int tid = blockIdx.x * 256 + threadIdx.x;   // 65536 = (b,l)
  int l = tid & (L - 1);
  int b = tid >> 10;
  const float* xp = x + (size_t)b * 65536 + l;
  float xv[64];
#pragma unroll
  for (int c = 0; c < 64; ++c) xv[c] = xp[c * L];
  float h[32];
#pragma unroll
  for (int d = 0; d < 32; ++d) {
    float acc = conv_b[d];
#pragma unroll
    for (int c = 0; c < 64; ++c) acc = fmaf(xv[c], conv_w[d * 64 + c], acc);
    float sc = gamma[d] * rsqrtf(var[d] + 1e-5f);
    acc = (acc - mean[d]) * sc + beta[d];
    h[d] = 0.5f * acc * (1.0f + erff(acc * 0.70710678118654752f));
  }
  for (int j = 0; j < 64; ++j) {
    float a0 = 0.f, a1 = 0.f;
#pragma unroll
    for (int d = 0; d < 32; ++d) {
      a0 = fmaf(h[d], ipw[j * 32 + d], a0);
      a1 = fmaf(h[d], ipw[(j + 64) * 32 + d], a1);
    }
    xm[(size_t)b * 65536 + j * L + l] = f2b(a0);
    z [(size_t)b * 65536 + j * L + l] = f2b(a1);
  }
}

// ---- k_mid: depthwise conv1d + SiLU + x_proj + dt(softplus) ----
// B/C written pre-permuted for the scan's LDS layout:
// element idx (per batch) = n4*4096 + i*128 + c*4 + nn,
// where i = l&31 (step in chunk), c = l>>5 (chunk), n = n4*4+nn.
__global__ __launch_bounds__(256) void k_mid(
    const bf* __restrict__ xm, const float* __restrict__ c1w,
    const float* __restrict__ c1b, const float* __restrict__ xpw,
    const float* __restrict__ dtw, const float* __restrict__ dtbp,
    bf* __restrict__ u, bf* __restrict__ dt_o,
    bf* __restrict__ Bt, bf* __restrict__ Ct) {
  int tid = blockIdx.x * 256 + threadIdx.x;   // (b,l)
  int l = tid & (L - 1);
  int b = tid >> 10;
  float um[64];
#pragma unroll
  for (int d = 0; d < 64; ++d) {
    float acc = c1b[d];
#pragma unroll
    for (int k = 0; k < 4; ++k) {
      int ls = l - 3 + k;
      float v = (ls >= 0) ? b2f(xm[(size_t)b * 65536 + d * L + ls]) : 0.f;
      acc = fmaf(c1w[d * 4 + k], v, acc);
    }
    float s = acc / (1.f + __expf(-acc));
    um[d] = s;
    u[(size_t)b * 65536 + d * L + l] = f2b(s);
  }
  float xd[34];
  for (int k = 0; k < 34; ++k) {
    float acc = 0.f;
#pragma unroll
    for (int d = 0; d < 64; ++d) acc = fmaf(um[d], xpw[k * 64 + d], acc);
    xd[k] = acc;
  }
#pragma unroll
  for (int d = 0; d < 64; ++d) {
    float raw = fmaf(xd[0], dtw[d * 2], fmaf(xd[1], dtw[d * 2 + 1], dtbp[d]));
    float sp = fmaxf(raw, 0.f) + log1pf(__expf(-fabsf(raw)));
    dt_o[(size_t)b * 65536 + d * L + l] = f2b(sp);
  }
  int i = l & 31, c = l >> 5;
  size_t basei = ((size_t)b * 16384 + (size_t)i * 128 + c * 4) >> 2; // short4 idx
  short4v* B4 = (short4v*)Bt;
  short4v* C4 = (short4v*)Ct;
#pragma unroll
  for (int n4 = 0; n4 < 4; ++n4) {
    Pack4 pb, pc;
#pragma unroll
    for (int nn = 0; nn < 4; ++nn) {
      pb.e[nn] = f2bits(xd[2 + n4 * 4 + nn]);
      pc.e[nn] = f2bits(xd[18 + n4 * 4 + nn]);
    }
    B4[basei + (size_t)n4 * 1024] = pb.v;
    C4[basei + (size_t)n4 * 1024] = pc.v;
  }
}

// ---- k_scan: single-sweep chunked scan, B/C in LDS (b64 quads), gate+pool --
// block = (b, 8 d's), 256 thr = 8 d x 32 chunks of 32 steps. Grid 512.
__global__ __launch_bounds__(256, 2) void k_scan(
    const bf* __restrict__ u, const bf* __restrict__ dt,
    const bf* __restrict__ z, const bf* __restrict__ Bt,
    const bf* __restrict__ Ct, const float* __restrict__ A_log,
    const float* __restrict__ Dp, float* __restrict__ pooled64) {
  __shared__ bf Bsh[16384];   // 32 KB, [n4][step][chunk] quads
  __shared__ bf Csh[16384];   // 32 KB
  int phys = blockIdx.x;      // 512 blocks
  int b = phys & 63;
  int dgrp = phys >> 6;       // 0..7
  int t = threadIdx.x;
  int d_local = t >> 5, c = t & 31;
  int d = dgrp * 8 + d_local;
  int g = b * 64 + d;

  // stage both panels: 2048 short8 each, 8 per thread (linear, conflict-free)
  {
    const short8v* Bg8 = (const short8v*)(Bt + (size_t)b * 16384);
    const short8v* Cg8 = (const short8v*)(Ct + (size_t)b * 16384);
    short8v* Bs8 = (short8v*)Bsh;
    short8v* Cs8 = (short8v*)Csh;
#pragma unroll
    for (int q = 0; q < 8; ++q) {
      Bs8[t + q * 256] = Bg8[t + q * 256];
      Cs8[t + q * 256] = Cg8[t + q * 256];
    }
  }
  __syncthreads();

  float An[16];
#pragma unroll
  for (int n = 0; n < 16; ++n) An[n] = -__expf(A_log[d * 16 + n]);
  const short4v* dps = (const short4v*)(dt + (size_t)g * L + c * 32);
  const short4v* ups = (const short4v*)(u  + (size_t)g * L + c * 32);
  const short4v* zps = (const short4v*)(z  + (size_t)g * L + c * 32);
  const short4v* Bs4 = (const short4v*)Bsh;
  const short4v* Cs4 = (const short4v*)Csh;
  float Dd = Dp[d];

  float h[16], pi[16], q[16];
#pragma unroll
  for (int n = 0; n < 16; ++n) { h[n] = 0.f; pi[n] = 1.f; q[n] = 0.f; }
  float base = 0.f;

#pragma unroll 1
  for (int t4 = 0; t4 < 8; ++t4) {
    short4v d4 = dps[t4], u4 = ups[t4], z4 = zps[t4];
#pragma unroll
    for (int i = 0; i < 4; ++i) {
      int step = t4 * 4 + i;
      float dtv = bits2f(d4[i]);
      float uv  = bits2f(u4[i]);
      float zv  = bits2f(z4[i]);
      float sv  = zv / (1.f + __expf(-zv));   // silu(z)
      float du  = dtv * uv;
      int slot = step * 32 + c;
      float y0 = 0.f, y1 = 0.f;
#pragma unroll
      for (int n4 = 0; n4 < 4; ++n4) {
        short4v bq = Bs4[n4 * 1024 + slot];   // ds_read_b64, 2-way (free)
        short4v cq = Cs4[n4 * 1024 + slot];
#pragma unroll
        for (int nn = 0; nn < 4; ++nn) {
          int n = n4 * 4 + nn;
          float a = __expf(dtv * An[n]);
          float Bv = bits2f(bq[nn]);
          float Cv = bits2f(cq[nn]);
          h[n] = fmaf(a, h[n], du * Bv);
          pi[n] *= a;
          if (nn & 1) y1 = fmaf(h[n], Cv, y1); else y0 = fmaf(h[n], Cv, y0);
          q[n] = fmaf(sv * pi[n], Cv, q[n]);
        }
      }
      base = fmaf(sv, (y0 + y1) + uv * Dd, base);
    }
  }

  // ---- compose over 32 chunks (width-32 Hillis-Steele): P=pi, O=h ----
#pragma unroll
  for (int s = 1; s < 32; s <<= 1) {
    bool act = (c >= s);
#pragma unroll
    for (int n = 0; n < 16; ++n) {
      float Po = __shfl_up(pi[n], (unsigned)s, 32);
      float Oo = __shfl_up(h[n], (unsigned)s, 32);
      if (act) { h[n] = fmaf(pi[n], Oo, h[n]); pi[n] *= Po; }
    }
  }
  float pooled = base;
#pragma unroll
  for (int n = 0; n < 16; ++n) {
    float v = __shfl_up(h[n], 1u, 32);
    float hin = (c == 0) ? 0.f : v;       // exclusive prefix = h_in
    pooled = fmaf(q[n], hin, pooled);
  }
#pragma unroll
  for (int s = 1; s < 32; s <<= 1) pooled += __shfl_xor(pooled, s, 32);
  if (c == 0) pooled64[g] = pooled;
}

// ---- k_fc: out_proj(mean) + fc (out_proj commutes with mean-pool) ----
__global__ __launch_bounds__(128) void k_fc(
    const float* __restrict__ pooled64, const float* __restrict__ opw,
    const float* __restrict__ fcw, const float* __restrict__ fcb,
    float* __restrict__ out) {
  __shared__ float p64[64];
  __shared__ float o32[32];
  int b = blockIdx.x, t = threadIdx.x;
  if (t < 64) p64[t] = pooled64[b * 64 + t];
  __syncthreads();
  if (t < 32) {
    float s = 0.f;
#pragma unroll
    for (int d0 = 0; d0 < 64; ++d0) s = fmaf(p64[d0], opw[t * 64 + d0], s);
    o32[t] = s * (1.f / 1024.f);
  }
  __syncthreads();
  float acc = fcb[t];
#pragma unroll
  for (int j = 0; j < 32; ++j) acc = fmaf(o32[j], fcw[t * 32 + j], acc);
  out[b * 128 + t] = acc;
}

extern "C" void kernel_launch(void* const* d_in, const int* in_sizes, int n_in,
                              void* d_out, int out_size, void* d_ws, size_t ws_size,
                              hipStream_t stream) {
  const float* x      = (const float*)d_in[0];
  const float* conv_w = (const float*)d_in[1];
  const float* conv_b = (const float*)d_in[2];
  const float* bn_g   = (const float*)d_in[3];
  const float* bn_b   = (const float*)d_in[4];
  const float* bn_m   = (const float*)d_in[5];
  const float* bn_v   = (const float*)d_in[6];
  const float* ipw    = (const float*)d_in[7];
  const float* c1w    = (const float*)d_in[8];
  const float* c1b    = (const float*)d_in[9];
  const float* xpw    = (const float*)d_in[10];
  const float* dtw    = (const float*)d_in[11];
  const float* dtbp   = (const float*)d_in[12];
  const float* A_log  = (const float*)d_in[13];
  const float* Dp     = (const float*)d_in[14];
  const float* opw    = (const float*)d_in[15];
  const float* fcw    = (const float*)d_in[16];
  const float* fcb    = (const float*)d_in[17];

  char* ws = (char*)d_ws;
  bf* xmb = (bf*)(ws + 0);               // 8 MB
  bf* zb  = (bf*)(ws + 8388608);         // 8 MB
  bf* ub  = (bf*)(ws + 16777216);        // 8 MB
  bf* dtb = (bf*)(ws + 25165824);        // 8 MB
  bf* Btb = (bf*)(ws + 33554432);        // 2 MB (quad-permuted)
  bf* Ctb = (bf*)(ws + 35651584);        // 2 MB (quad-permuted)
  float* pooled = (float*)(ws + 37748736); // 16 KB

  hipLaunchKernelGGL(k_front, dim3(256), dim3(256), 0, stream,
                     x, conv_w, conv_b, bn_g, bn_b, bn_m, bn_v, ipw, xmb, zb);
  hipLaunchKernelGGL(k_mid, dim3(256), dim3(256), 0, stream,
                     xmb, c1w, c1b, xpw, dtw, dtbp, ub, dtb, Btb, Ctb);
  hipLaunchKernelGGL(k_scan, dim3(512), dim3(256), 0, stream,
                     ub, dtb, zb, Btb, Ctb, A_log, Dp, pooled);
  hipLaunchKernelGGL(k_fc, dim3(64), dim3(128), 0, stream,
                     pooled, opw, fcw, fcb, (float*)d_out);
}

// Round 12
// 150.239 us; speedup vs baseline: 4.0695x; 1.2512x over previous
//
#include <hip/hip_runtime.h>
#include <hip/hip_bf16.h>
#include <math.h>

#define L 1024
typedef __hip_bfloat16 bf;
typedef __attribute__((ext_vector_type(8))) short short8v;
typedef __attribute__((ext_vector_type(4))) short short4v;

__device__ __forceinline__ float b2f(bf v) { return __bfloat162float(v); }
__device__ __forceinline__ bf f2b(float v) { return __float2bfloat16(v); }
__device__ __forceinline__ float bits2f(short s) {
  union { unsigned u; float f; } cv; cv.u = ((unsigned)(unsigned short)s) << 16; return cv.f;
}
union Pack4 { short4v v; unsigned short e[4]; };
union Pack8 { short8v v; unsigned short e[8]; };
__device__ __forceinline__ unsigned short f2bits(float v) {
  union { bf b; unsigned short u; } cv; cv.b = __float2bfloat16(v); return cv.u;
}

// ---- k_front: conv1x1+BN+GELU+in_proj. 2-way split: q=0 -> xm, q=1 -> z ----
// xm layout: (b, l, d) vector stores. z layout: (b, d, l) coalesced stores.
__global__ __launch_bounds__(256) void k_front(
    const float* __restrict__ x, const float* __restrict__ conv_w,
    const float* __restrict__ conv_b, const float* __restrict__ gamma,
    const float* __restrict__ beta, const float* __restrict__ mean,
    const float* __restrict__ var, const float* __restrict__ ipw,
    bf* __restrict__ xm, bf* __restrict__ z) {
  int t = threadIdx.x;
  int q = t >> 7;                  // 0: xm-half, 1: z-half (wave-uniform)
  int l = (blockIdx.x & 7) * 128 + (t & 127);
  int b = blockIdx.x >> 3;         // grid 512 = 64 b x 8 ltiles
  const float* xp = x + (size_t)b * 65536 + l;
  float xv[64];
#pragma unroll
  for (int c = 0; c < 64; ++c) xv[c] = xp[c * L];   // coalesced per wave
  float h[32];
#pragma unroll
  for (int d = 0; d < 32; ++d) {
    float acc = conv_b[d];
#pragma unroll
    for (int c = 0; c < 64; ++c) acc = fmaf(xv[c], conv_w[d * 64 + c], acc);
    float sc = gamma[d] * rsqrtf(var[d] + 1e-5f);
    acc = (acc - mean[d]) * sc + beta[d];
    h[d] = 0.5f * acc * (1.0f + erff(acc * 0.70710678118654752f));
  }
  if (q == 0) {
    bf* xrow = xm + (size_t)b * 65536 + (size_t)l * 64;
    short8v* xr8 = (short8v*)xrow;
#pragma unroll
    for (int c8 = 0; c8 < 8; ++c8) {
      Pack8 p;
#pragma unroll
      for (int e = 0; e < 8; ++e) {
        int j = c8 * 8 + e;
        float acc = 0.f;
#pragma unroll
        for (int d = 0; d < 32; ++d) acc = fmaf(h[d], ipw[j * 32 + d], acc);
        p.e[e] = f2bits(acc);
      }
      xr8[c8] = p.v;               // 16B store, contiguous 128B per thread
    }
  } else {
    bf* zp = z + (size_t)b * 65536 + l;
#pragma unroll
    for (int j = 0; j < 64; ++j) {
      float acc = 0.f;
#pragma unroll
      for (int d = 0; d < 32; ++d) acc = fmaf(h[d], ipw[(j + 64) * 32 + d], acc);
      zp[(size_t)j * L] = f2b(acc);   // coalesced 128B per instr across lanes
    }
  }
}

// ---- k_mid: conv1d+SiLU+x_proj+dt. 2-way split: qk=0 -> dt+B, qk=1 -> u+C --
// xm read from (b,l,d) with vector loads; u/dt (b,d,l); B/C quad-permuted.
__global__ __launch_bounds__(256) void k_mid(
    const bf* __restrict__ xm, const float* __restrict__ c1w,
    const float* __restrict__ c1b, const float* __restrict__ xpw,
    const float* __restrict__ dtw, const float* __restrict__ dtbp,
    bf* __restrict__ u, bf* __restrict__ dt_o,
    bf* __restrict__ Bt, bf* __restrict__ Ct) {
  int t = threadIdx.x;
  int qk = t >> 7;                 // 0: dt+B, 1: u+C (wave-uniform)
  int l = (blockIdx.x & 7) * 128 + (t & 127);
  int b = blockIdx.x >> 3;         // grid 512
  float um[64];
#pragma unroll
  for (int d = 0; d < 64; ++d) um[d] = c1b[d];
#pragma unroll
  for (int k = 0; k < 4; ++k) {
    int lr = l - 3 + k;
    if (lr >= 0) {
      const short8v* row = (const short8v*)(xm + (size_t)b * 65536 + (size_t)lr * 64);
#pragma unroll
      for (int d8 = 0; d8 < 8; ++d8) {
        short8v v = row[d8];
#pragma unroll
        for (int e = 0; e < 8; ++e)
          um[d8 * 8 + e] = fmaf(c1w[(d8 * 8 + e) * 4 + k], bits2f(v[e]), um[d8 * 8 + e]);
      }
    }
  }
#pragma unroll
  for (int d = 0; d < 64; ++d) {
    float s = um[d];
    um[d] = s / (1.f + __expf(-s));   // silu
  }
  int i = l & 31, c = l >> 5;
  if (qk == 0) {
    // x_dbl k = 0..17 : dt (k 0,1) + B (k 2..17)
    float xd[18];
#pragma unroll
    for (int k = 0; k < 18; ++k) {
      float acc = 0.f;
#pragma unroll
      for (int d = 0; d < 64; ++d) acc = fmaf(um[d], xpw[k * 64 + d], acc);
      xd[k] = acc;
    }
    bf* dp = dt_o + (size_t)b * 65536 + l;
#pragma unroll
    for (int d = 0; d < 64; ++d) {
      float raw = fmaf(xd[0], dtw[d * 2], fmaf(xd[1], dtw[d * 2 + 1], dtbp[d]));
      float sp = fmaxf(raw, 0.f) + log1pf(__expf(-fabsf(raw)));
      dp[(size_t)d * L] = f2b(sp);
    }
    size_t basei = ((size_t)b * 16384 + (size_t)i * 128 + c * 4) >> 2;
    short4v* B4 = (short4v*)Bt;
#pragma unroll
    for (int n4 = 0; n4 < 4; ++n4) {
      Pack4 pb;
#pragma unroll
      for (int nn = 0; nn < 4; ++nn) pb.e[nn] = f2bits(xd[2 + n4 * 4 + nn]);
      B4[basei + (size_t)n4 * 1024] = pb.v;
    }
  } else {
    // u writes + x_dbl k = 18..33 : C
    bf* up = u + (size_t)b * 65536 + l;
#pragma unroll
    for (int d = 0; d < 64; ++d) up[(size_t)d * L] = f2b(um[d]);
    float xd[16];
#pragma unroll
    for (int k = 0; k < 16; ++k) {
      float acc = 0.f;
#pragma unroll
      for (int d = 0; d < 64; ++d) acc = fmaf(um[d], xpw[(18 + k) * 64 + d], acc);
      xd[k] = acc;
    }
    size_t basei = ((size_t)b * 16384 + (size_t)i * 128 + c * 4) >> 2;
    short4v* C4 = (short4v*)Ct;
#pragma unroll
    for (int n4 = 0; n4 < 4; ++n4) {
      Pack4 pc;
#pragma unroll
      for (int nn = 0; nn < 4; ++nn) pc.e[nn] = f2bits(xd[n4 * 4 + nn]);
      C4[basei + (size_t)n4 * 1024] = pc.v;
    }
  }
}

// ---- k_scan: single-sweep chunked scan, B/C in LDS (b64 quads), gate+pool --
__global__ __launch_bounds__(256, 2) void k_scan(
    const bf* __restrict__ u, const bf* __restrict__ dt,
    const bf* __restrict__ z, const bf* __restrict__ Bt,
    const bf* __restrict__ Ct, const float* __restrict__ A_log,
    const float* __restrict__ Dp, float* __restrict__ pooled64) {
  __shared__ bf Bsh[16384];   // 32 KB, [n4][step][chunk] quads
  __shared__ bf Csh[16384];   // 32 KB
  int phys = blockIdx.x;      // 512 blocks
  int b = phys & 63;
  int dgrp = phys >> 6;       // 0..7
  int t = threadIdx.x;
  int d_local = t >> 5, c = t & 31;
  int d = dgrp * 8 + d_local;
  int g = b * 64 + d;

  {
    const short8v* Bg8 = (const short8v*)(Bt + (size_t)b * 16384);
    const short8v* Cg8 = (const short8v*)(Ct + (size_t)b * 16384);
    short8v* Bs8 = (short8v*)Bsh;
    short8v* Cs8 = (short8v*)Csh;
#pragma unroll
    for (int q = 0; q < 8; ++q) {
      Bs8[t + q * 256] = Bg8[t + q * 256];
      Cs8[t + q * 256] = Cg8[t + q * 256];
    }
  }
  __syncthreads();

  float An[16];
#pragma unroll
  for (int n = 0; n < 16; ++n) An[n] = -__expf(A_log[d * 16 + n]);
  const short4v* dps = (const short4v*)(dt + (size_t)g * L + c * 32);
  const short4v* ups = (const short4v*)(u  + (size_t)g * L + c * 32);
  const short4v* zps = (const short4v*)(z  + (size_t)g * L + c * 32);
  const short4v* Bs4 = (const short4v*)Bsh;
  const short4v* Cs4 = (const short4v*)Csh;
  float Dd = Dp[d];

  float h[16], pi[16], q[16];
#pragma unroll
  for (int n = 0; n < 16; ++n) { h[n] = 0.f; pi[n] = 1.f; q[n] = 0.f; }
  float base = 0.f;

#pragma unroll 1
  for (int t4 = 0; t4 < 8; ++t4) {
    short4v d4 = dps[t4], u4 = ups[t4], z4 = zps[t4];
#pragma unroll
    for (int i = 0; i < 4; ++i) {
      int step = t4 * 4 + i;
      float dtv = bits2f(d4[i]);
      float uv  = bits2f(u4[i]);
      float zv  = bits2f(z4[i]);
      float sv  = zv / (1.f + __expf(-zv));
      float du  = dtv * uv;
      int slot = step * 32 + c;
      float y0 = 0.f, y1 = 0.f;
#pragma unroll
      for (int n4 = 0; n4 < 4; ++n4) {
        short4v bq = Bs4[n4 * 1024 + slot];
        short4v cq = Cs4[n4 * 1024 + slot];
#pragma unroll
        for (int nn = 0; nn < 4; ++nn) {
          int n = n4 * 4 + nn;
          float a = __expf(dtv * An[n]);
          float Bv = bits2f(bq[nn]);
          float Cv = bits2f(cq[nn]);
          h[n] = fmaf(a, h[n], du * Bv);
          pi[n] *= a;
          if (nn & 1) y1 = fmaf(h[n], Cv, y1); else y0 = fmaf(h[n], Cv, y0);
          q[n] = fmaf(sv * pi[n], Cv, q[n]);
        }
      }
      base = fmaf(sv, (y0 + y1) + uv * Dd, base);
    }
  }

#pragma unroll
  for (int s = 1; s < 32; s <<= 1) {
    bool act = (c >= s);
#pragma unroll
    for (int n = 0; n < 16; ++n) {
      float Po = __shfl_up(pi[n], (unsigned)s, 32);
      float Oo = __shfl_up(h[n], (unsigned)s, 32);
      if (act) { h[n] = fmaf(pi[n], Oo, h[n]); pi[n] *= Po; }
    }
  }
  float pooled = base;
#pragma unroll
  for (int n = 0; n < 16; ++n) {
    float v = __shfl_up(h[n], 1u, 32);
    float hin = (c == 0) ? 0.f : v;
    pooled = fmaf(q[n], hin, pooled);
  }
#pragma unroll
  for (int s = 1; s < 32; s <<= 1) pooled += __shfl_xor(pooled, s, 32);
  if (c == 0) pooled64[g] = pooled;
}

// ---- k_fc: out_proj(mean) + fc ----
__global__ __launch_bounds__(128) void k_fc(
    const float* __restrict__ pooled64, const float* __restrict__ opw,
    const float* __restrict__ fcw, const float* __restrict__ fcb,
    float* __restrict__ out) {
  __shared__ float p64[64];
  __shared__ float o32[32];
  int b = blockIdx.x, t = threadIdx.x;
  if (t < 64) p64[t] = pooled64[b * 64 + t];
  __syncthreads();
  if (t < 32) {
    float s = 0.f;
#pragma unroll
    for (int d0 = 0; d0 < 64; ++d0) s = fmaf(p64[d0], opw[t * 64 + d0], s);
    o32[t] = s * (1.f / 1024.f);
  }
  __syncthreads();
  float acc = fcb[t];
#pragma unroll
  for (int j = 0; j < 32; ++j) acc = fmaf(o32[j], fcw[t * 32 + j], acc);
  out[b * 128 + t] = acc;
}

extern "C" void kernel_launch(void* const* d_in, const int* in_sizes, int n_in,
                              void* d_out, int out_size, void* d_ws, size_t ws_size,
                              hipStream_t stream) {
  const float* x      = (const float*)d_in[0];
  const float* conv_w = (const float*)d_in[1];
  const float* conv_b = (const float*)d_in[2];
  const float* bn_g   = (const float*)d_in[3];
  const float* bn_b   = (const float*)d_in[4];
  const float* bn_m   = (const float*)d_in[5];
  const float* bn_v   = (const float*)d_in[6];
  const float* ipw    = (const float*)d_in[7];
  const float* c1w    = (const float*)d_in[8];
  const float* c1b    = (const float*)d_in[9];
  const float* xpw    = (const float*)d_in[10];
  const float* dtw    = (const float*)d_in[11];
  const float* dtbp   = (const float*)d_in[12];
  const float* A_log  = (const float*)d_in[13];
  const float* Dp     = (const float*)d_in[14];
  const float* opw    = (const float*)d_in[15];
  const float* fcw    = (const float*)d_in[16];
  const float* fcb    = (const float*)d_in[17];

  char* ws = (char*)d_ws;
  bf* xmb = (bf*)(ws + 0);               // 8 MB (b,l,d)
  bf* zb  = (bf*)(ws + 8388608);         // 8 MB (b,d,l)
  bf* ub  = (bf*)(ws + 16777216);        // 8 MB (b,d,l)
  bf* dtb = (bf*)(ws + 25165824);        // 8 MB (b,d,l)
  bf* Btb = (bf*)(ws + 33554432);        // 2 MB (quad-permuted)
  bf* Ctb = (bf*)(ws + 35651584);        // 2 MB (quad-permuted)
  float* pooled = (float*)(ws + 37748736); // 16 KB

  hipLaunchKernelGGL(k_front, dim3(512), dim3(256), 0, stream,
                     x, conv_w, conv_b, bn_g, bn_b, bn_m, bn_v, ipw, xmb, zb);
  hipLaunchKernelGGL(k_mid, dim3(512), dim3(256), 0, stream,
                     xmb, c1w, c1b, xpw, dtw, dtbp, ub, dtb, Btb, Ctb);
  hipLaunchKernelGGL(k_scan, dim3(512), dim3(256), 0, stream,
                     ub, dtb, zb, Btb, Ctb, A_log, Dp, pooled);
  hipLaunchKernelGGL(k_fc, dim3(64), dim3(128), 0, stream,
                     pooled, opw, fcw, fcb, (float*)d_out);
}